// Round 1
// baseline (234.221 us; speedup 1.0000x reference)
//
#include <hip/hip_runtime.h>
#include <stdint.h>

#define EPSF 1e-8f

using bf16x8 = __attribute__((ext_vector_type(8))) __bf16;
using f32x4  = __attribute__((ext_vector_type(4))) float;

__device__ __forceinline__ unsigned short f32_to_bf16(float f) {
  union { float f; unsigned int u; } v; v.f = f;
  unsigned int r = (v.u + 0x7FFFu + ((v.u >> 16) & 1u)) >> 16;  // RNE
  return (unsigned short)r;
}

__device__ __forceinline__ float wave_sum(float v) {
#pragma unroll
  for (int off = 32; off > 0; off >>= 1) v += __shfl_down(v, off, 64);
  return v;
}

// ---------------- weight ternary quant + per-row scale ----------------
// One block per weight row (K = 2048, 256 threads x 8 elems).
// mask: |w| > 0.5*mean|w| is invariant to row RMSNorm (positive factor cancels).
// scale[o] = mean|w| * rsqrt(mean(w^2)+EPS) * row_scale[o]
__global__ __launch_bounds__(256) void wquant_kernel(
    const float* __restrict__ w, const float* __restrict__ row_scale,
    unsigned short* __restrict__ wq, float* __restrict__ scale, int K) {
  const int row = blockIdx.x;
  const int t = threadIdx.x;
  const float* wr = w + (size_t)row * K;
  float4 v0 = reinterpret_cast<const float4*>(wr)[2 * t];
  float4 v1 = reinterpret_cast<const float4*>(wr)[2 * t + 1];
  float f[8] = {v0.x, v0.y, v0.z, v0.w, v1.x, v1.y, v1.z, v1.w};
  float sa = 0.f, sq = 0.f;
#pragma unroll
  for (int i = 0; i < 8; ++i) { sa += fabsf(f[i]); sq += f[i] * f[i]; }
  sa = wave_sum(sa);
  sq = wave_sum(sq);
  __shared__ float smA[4], smQ[4];
  const int wid = t >> 6;
  if ((t & 63) == 0) { smA[wid] = sa; smQ[wid] = sq; }
  __syncthreads();
  const float sumabs = smA[0] + smA[1] + smA[2] + smA[3];
  const float sumsq  = smQ[0] + smQ[1] + smQ[2] + smQ[3];
  const float absmean = sumabs / (float)K;
  const float thr = 0.5f * absmean;
  union { unsigned short s[8]; uint4 u; } pk;
#pragma unroll
  for (int i = 0; i < 8; ++i)
    pk.s[i] = (fabsf(f[i]) > thr) ? (f[i] > 0.f ? (unsigned short)0x3F80u
                                                : (unsigned short)0xBF80u)
                                  : (unsigned short)0u;  // bf16 {-1,0,1} exact
  reinterpret_cast<uint4*>(wq + (size_t)row * K)[t] = pk.u;
  if (t == 0)
    scale[row] = absmean * rsqrtf(sumsq / (float)K + EPSF) * row_scale[row];
}

// ---------------- input RMSNorm * g -> bf16 ----------------
// One block per (b,s) row. 256 threads x 8 elems, float4 loads, bf16x8 store.
__global__ __launch_bounds__(256) void xnorm_kernel(
    const float* __restrict__ x, const float* __restrict__ g,
    unsigned short* __restrict__ xn, int K) {
  const int row = blockIdx.x;
  const int t = threadIdx.x;
  const float* xr = x + (size_t)row * K;
  float4 v0 = reinterpret_cast<const float4*>(xr)[2 * t];
  float4 v1 = reinterpret_cast<const float4*>(xr)[2 * t + 1];
  float f[8] = {v0.x, v0.y, v0.z, v0.w, v1.x, v1.y, v1.z, v1.w};
  float sq = 0.f;
#pragma unroll
  for (int i = 0; i < 8; ++i) sq += f[i] * f[i];
  sq = wave_sum(sq);
  __shared__ float smQ[4];
  const int wid = t >> 6;
  if ((t & 63) == 0) smQ[wid] = sq;
  __syncthreads();
  const float sumsq = smQ[0] + smQ[1] + smQ[2] + smQ[3];
  const float rs = rsqrtf(sumsq / (float)K + EPSF);
  float4 g0 = reinterpret_cast<const float4*>(g)[2 * t];
  float4 g1 = reinterpret_cast<const float4*>(g)[2 * t + 1];
  float gg[8] = {g0.x, g0.y, g0.z, g0.w, g1.x, g1.y, g1.z, g1.w};
  union { unsigned short s[8]; uint4 u; } pk;
#pragma unroll
  for (int i = 0; i < 8; ++i) pk.s[i] = f32_to_bf16(f[i] * rs * gg[i]);
  reinterpret_cast<uint4*>(xn + (size_t)row * K)[t] = pk.u;
}

// ---------------- bf16 NT GEMM (m97 structure) ----------------
// C[m,n] = scale[n] * sum_k A[m,k]*B[n,k] + bias[n]
// BM=BN=128, BK=64, 256 threads = 4 waves (2x2), each wave 64x64 out,
// 16x16x32 MFMA, global_load_lds width=16 staging, linear LDS.
#define BM 128
#define BN 128
#define BK 64

__global__ __launch_bounds__(256) void gemm_kernel(
    const unsigned short* __restrict__ A,   // [M][K] bf16 (xn)
    const unsigned short* __restrict__ Bq,  // [N][K] bf16 ternary (wq)
    const float* __restrict__ scale, const float* __restrict__ bias,
    float* __restrict__ C, int M, int N, int K) {
  __shared__ unsigned short As[BM * BK];
  __shared__ unsigned short Bs[BN * BK];
  const int tid = threadIdx.x;
  const int lane = tid & 63;
  const int wid = tid >> 6;
  const int wm = wid >> 1, wn = wid & 1;
  const int mBase = blockIdx.y * BM, nBase = blockIdx.x * BN;

  // staging map: thread t covers 16B = 8 bf16 at tile row t/8, col (t%8)*8,
  // plus rr*32 rows per round. LDS dest = wave-uniform base + lane*16 (required).
  const int srow = tid >> 3;
  const int scol = (tid & 7) * 8;
  const unsigned short* aSrc = A + (size_t)(mBase + srow) * K + scol;
  const unsigned short* bSrc = Bq + (size_t)(nBase + srow) * K + scol;

  f32x4 acc[4][4];
#pragma unroll
  for (int m = 0; m < 4; ++m)
#pragma unroll
    for (int n = 0; n < 4; ++n) acc[m][n] = (f32x4){0.f, 0.f, 0.f, 0.f};

  const int fr = lane & 15;        // A-frag row / B-frag col
  const int kb = (lane >> 4) * 8;  // k sub-offset within 32

  for (int k0 = 0; k0 < K; k0 += BK) {
#pragma unroll
    for (int rr = 0; rr < 4; ++rr) {
      const int idx = rr * 2048 + tid * 8;  // bf16 elements into LDS
      __builtin_amdgcn_global_load_lds(
          (const __attribute__((address_space(1))) void*)(aSrc + k0 + rr * 32 * K),
          (__attribute__((address_space(3))) void*)(&As[idx]), 16, 0, 0);
      __builtin_amdgcn_global_load_lds(
          (const __attribute__((address_space(1))) void*)(bSrc + k0 + rr * 32 * K),
          (__attribute__((address_space(3))) void*)(&Bs[idx]), 16, 0, 0);
    }
    __syncthreads();  // drains vmcnt before barrier (compiler-emitted)

#pragma unroll
    for (int kk = 0; kk < BK; kk += 32) {
      bf16x8 af[4], bfr[4];
#pragma unroll
      for (int m = 0; m < 4; ++m)
        af[m] = *reinterpret_cast<const bf16x8*>(
            &As[(wm * 64 + m * 16 + fr) * BK + kk + kb]);
#pragma unroll
      for (int n = 0; n < 4; ++n)
        bfr[n] = *reinterpret_cast<const bf16x8*>(
            &Bs[(wn * 64 + n * 16 + fr) * BK + kk + kb]);
#pragma unroll
      for (int m = 0; m < 4; ++m)
#pragma unroll
        for (int n = 0; n < 4; ++n)
          acc[m][n] = __builtin_amdgcn_mfma_f32_16x16x32_bf16(
              af[m], bfr[n], acc[m][n], 0, 0, 0);
    }
    __syncthreads();
  }

  // epilogue: C/D layout col=lane&15, row=(lane>>4)*4+reg (m89/m91 verified)
  const int colf = lane & 15;
  const int rowg = (lane >> 4) * 4;
#pragma unroll
  for (int n = 0; n < 4; ++n) {
    const int gc = nBase + wn * 64 + n * 16 + colf;
    const float sc = scale[gc];
    const float bi = bias[gc];
#pragma unroll
    for (int m = 0; m < 4; ++m) {
      const size_t gr = (size_t)(mBase + wm * 64 + m * 16 + rowg);
#pragma unroll
      for (int r = 0; r < 4; ++r)
        C[(gr + (size_t)r) * (size_t)N + (size_t)gc] = acc[m][n][r] * sc + bi;
    }
  }
}

extern "C" void kernel_launch(void* const* d_in, const int* in_sizes, int n_in,
                              void* d_out, int out_size, void* d_ws, size_t ws_size,
                              hipStream_t stream) {
  const float* x         = (const float*)d_in[0];  // [B,S,Din]
  const float* weight    = (const float*)d_in[1];  // [Dout,Din]
  const float* row_scale = (const float*)d_in[2];  // [Dout,1]
  const float* bias      = (const float*)d_in[3];  // [Dout]
  const float* g         = (const float*)d_in[4];  // [Din]
  float* out = (float*)d_out;

  const int Din  = in_sizes[4];             // 2048
  const int Dout = in_sizes[3];             // 2048
  const int Mrows = in_sizes[0] / Din;      // 16384

  // workspace layout: wq bf16 [Dout*Din] | xn bf16 [M*Din] | scale f32 [Dout]
  char* ws = (char*)d_ws;
  unsigned short* wq = (unsigned short*)ws;
  unsigned short* xn = (unsigned short*)(ws + (size_t)Dout * Din * 2);
  float* scale = (float*)(ws + (size_t)Dout * Din * 2 + (size_t)Mrows * Din * 2);

  wquant_kernel<<<Dout, 256, 0, stream>>>(weight, row_scale, wq, scale, Din);
  xnorm_kernel<<<Mrows, 256, 0, stream>>>(x, g, xn, Din);
  gemm_kernel<<<dim3(Dout / BN, Mrows / BM), 256, 0, stream>>>(
      xn, wq, scale, bias, out, Mrows, Dout, Din);
}

// Round 2
// 171.086 us; speedup vs baseline: 1.3690x; 1.3690x over previous
//
#include <hip/hip_runtime.h>
#include <stdint.h>

#define EPSF 1e-8f

using bf16x8 = __attribute__((ext_vector_type(8))) __bf16;
using f32x4  = __attribute__((ext_vector_type(4))) float;

__device__ __forceinline__ unsigned short f32_to_bf16(float f) {
  union { float f; unsigned int u; } v; v.f = f;
  unsigned int r = (v.u + 0x7FFFu + ((v.u >> 16) & 1u)) >> 16;  // RNE
  return (unsigned short)r;
}

__device__ __forceinline__ float wave_sum(float v) {
#pragma unroll
  for (int off = 32; off > 0; off >>= 1) v += __shfl_down(v, off, 64);
  return v;
}

// ---------------- weight ternary quant + per-row scale ----------------
__global__ __launch_bounds__(256) void wquant_kernel(
    const float* __restrict__ w, const float* __restrict__ row_scale,
    unsigned short* __restrict__ wq, float* __restrict__ scale, int K) {
  const int row = blockIdx.x;
  const int t = threadIdx.x;
  const float* wr = w + (size_t)row * K;
  float4 v0 = reinterpret_cast<const float4*>(wr)[2 * t];
  float4 v1 = reinterpret_cast<const float4*>(wr)[2 * t + 1];
  float f[8] = {v0.x, v0.y, v0.z, v0.w, v1.x, v1.y, v1.z, v1.w};
  float sa = 0.f, sq = 0.f;
#pragma unroll
  for (int i = 0; i < 8; ++i) { sa += fabsf(f[i]); sq += f[i] * f[i]; }
  sa = wave_sum(sa);
  sq = wave_sum(sq);
  __shared__ float smA[4], smQ[4];
  const int wid = t >> 6;
  if ((t & 63) == 0) { smA[wid] = sa; smQ[wid] = sq; }
  __syncthreads();
  const float sumabs = smA[0] + smA[1] + smA[2] + smA[3];
  const float sumsq  = smQ[0] + smQ[1] + smQ[2] + smQ[3];
  const float absmean = sumabs / (float)K;
  const float thr = 0.5f * absmean;
  union { unsigned short s[8]; uint4 u; } pk;
#pragma unroll
  for (int i = 0; i < 8; ++i)
    pk.s[i] = (fabsf(f[i]) > thr) ? (f[i] > 0.f ? (unsigned short)0x3F80u
                                                : (unsigned short)0xBF80u)
                                  : (unsigned short)0u;
  reinterpret_cast<uint4*>(wq + (size_t)row * K)[t] = pk.u;
  if (t == 0)
    scale[row] = absmean * rsqrtf(sumsq / (float)K + EPSF) * row_scale[row];
}

// ---------------- input RMSNorm * g -> bf16 ----------------
__global__ __launch_bounds__(256) void xnorm_kernel(
    const float* __restrict__ x, const float* __restrict__ g,
    unsigned short* __restrict__ xn, int K) {
  const int row = blockIdx.x;
  const int t = threadIdx.x;
  const float* xr = x + (size_t)row * K;
  float4 v0 = reinterpret_cast<const float4*>(xr)[2 * t];
  float4 v1 = reinterpret_cast<const float4*>(xr)[2 * t + 1];
  float f[8] = {v0.x, v0.y, v0.z, v0.w, v1.x, v1.y, v1.z, v1.w};
  float sq = 0.f;
#pragma unroll
  for (int i = 0; i < 8; ++i) sq += f[i] * f[i];
  sq = wave_sum(sq);
  __shared__ float smQ[4];
  const int wid = t >> 6;
  if ((t & 63) == 0) smQ[wid] = sq;
  __syncthreads();
  const float sumsq = smQ[0] + smQ[1] + smQ[2] + smQ[3];
  const float rs = rsqrtf(sumsq / (float)K + EPSF);
  float4 g0 = reinterpret_cast<const float4*>(g)[2 * t];
  float4 g1 = reinterpret_cast<const float4*>(g)[2 * t + 1];
  float gg[8] = {g0.x, g0.y, g0.z, g0.w, g1.x, g1.y, g1.z, g1.w};
  union { unsigned short s[8]; uint4 u; } pk;
#pragma unroll
  for (int i = 0; i < 8; ++i) pk.s[i] = f32_to_bf16(f[i] * rs * gg[i]);
  reinterpret_cast<uint4*>(xn + (size_t)row * K)[t] = pk.u;
}

// ---------------- bf16 NT GEMM, 256x256 tile, 8-phase pipeline ----------------
// C[m,n] = scale[n]*sum_k A[m,k]*B[n,k] + bias[n]
// 512 threads = 8 waves (2M x 4N); per-wave 128x64 out; BK=64.
// LDS [buf][tensor][half][128*64] bf16 = 128 KiB. Half-tiles:
//   A half h = rows {wm*128 + h*64 .. +64} (quadrant rows m0-3 / m4-7)
//   B half h = rows {wn*64 + h*32 .. +32} (n0-1 / n2-3)
// Swizzle: storage byte col ^= ((storage_row & 7) << 4); staging pre-swizzles
// the GLOBAL source col (LDS write stays linear: global_load_lds requirement).
// Phase schedule (tile T0=2i in buf0, T1=2i+1 in buf1), one half-tile staged
// per phase, counted vmcnt so loads stay in flight across barriers:
//  P1 Q1(T0): LDA0h0+LDB0h0, stage A1h1(T1), vmcnt(6)
//  P2 Q2(T0): LDB0h1,        stage B1h1(T1)
//  P3 Q3(T0): LDA0h1,        stage A0h0(T0+2)
//  P4 Q4(T0): -              stage B0h0(T0+2), vmcnt(8)
//  P5 Q1(T1): LDA1h0+LDB1h0, stage A0h1(T0+2), vmcnt(6)
//  P6 Q2(T1): LDB1h1,        stage B0h1(T0+2)
//  P7 Q3(T1): LDA1h1,        stage A1h0(T1+2)
//  P8 Q4(T1): -              stage B1h0(T1+2), vmcnt(8)
// Tail: stage tile index clamped to NT-1 (keeps vmcnt counts uniform; the
// clamped stages land in slots that are never read again).

#define BAR() do { __builtin_amdgcn_sched_barrier(0); \
                   asm volatile("" ::: "memory"); \
                   __builtin_amdgcn_s_barrier(); \
                   asm volatile("" ::: "memory"); \
                   __builtin_amdgcn_sched_barrier(0); } while (0)
#define VM(n) asm volatile("s_waitcnt vmcnt(" #n ")" ::: "memory")

__global__ __launch_bounds__(512, 2) void gemm_kernel(
    const unsigned short* __restrict__ A,   // [M][K] bf16 (xn)
    const unsigned short* __restrict__ B,   // [N][K] bf16 ternary (wq)
    const float* __restrict__ scale, const float* __restrict__ bias,
    float* __restrict__ C, int M, int N, int K) {
  __shared__ unsigned short lds[2][2][2][8192];

  const int tid  = threadIdx.x;
  const int lane = tid & 63;
  const int wid  = tid >> 6;
  const int wm   = wid >> 2;   // 0..1
  const int wn   = wid & 3;    // 0..3
  const int fr   = lane & 15;
  const int kq   = lane >> 4;

  // XCD-aware block swizzle (nwg % 8 == 0 by construction)
  const int nwg = gridDim.x;
  const int cpx = nwg >> 3;
  const int swz = (blockIdx.x & 7) * cpx + (blockIdx.x >> 3);
  const int NBN = N >> 8;
  const int bn = swz % NBN;
  const int bm = swz / NBN;
  const int mBase = bm * 256, nBase = bn * 256;

  const size_t K2 = (size_t)K * 2;

  // ---- staging per-thread constants (pre-swizzled source col) ----
  const int srow = tid >> 3;                                   // 0..63
  const int scolswz = ((tid & 7) ^ (srow & 7)) << 4;           // byte
  const char* Abyte = (const char*)A + (size_t)(mBase + srow) * K2 + scolswz;
  const char* Bbyte = (const char*)B +
      (size_t)(nBase + ((srow >> 5) * 64) + (srow & 31)) * K2 + scolswz;

#define STAGE_A(bufi, h, t) do { \
    __builtin_amdgcn_global_load_lds( \
      (const __attribute__((address_space(1))) void*)(Abyte + (size_t)((h) * 64) * K2 + (size_t)(t) * 128), \
      (__attribute__((address_space(3))) void*)(&lds[bufi][0][h][tid * 8]), 16, 0, 0); \
    __builtin_amdgcn_global_load_lds( \
      (const __attribute__((address_space(1))) void*)(Abyte + (size_t)(128 + (h) * 64) * K2 + (size_t)(t) * 128), \
      (__attribute__((address_space(3))) void*)(&lds[bufi][0][h][4096 + tid * 8]), 16, 0, 0); \
  } while (0)

#define STAGE_B(bufi, h, t) do { \
    __builtin_amdgcn_global_load_lds( \
      (const __attribute__((address_space(1))) void*)(Bbyte + (size_t)((h) * 32) * K2 + (size_t)(t) * 128), \
      (__attribute__((address_space(3))) void*)(&lds[bufi][1][h][tid * 8]), 16, 0, 0); \
    __builtin_amdgcn_global_load_lds( \
      (const __attribute__((address_space(1))) void*)(Bbyte + (size_t)(128 + (h) * 32) * K2 + (size_t)(t) * 128), \
      (__attribute__((address_space(3))) void*)(&lds[bufi][1][h][4096 + tid * 8]), 16, 0, 0); \
  } while (0)

  // ---- ds_read per-thread constants (swizzled read col) ----
  const int cbi0 = ((kq ^ (fr & 7)) << 3);        // elem offset, kk=0
  const int cbi1 = (((4 ^ kq) ^ (fr & 7)) << 3);  // elem offset, kk=1
  const int aRow = (wm * 64 + fr) * 64;
  const int bRow = (wn * 32 + fr) * 64;

  bf16x8 aF[4][2], bF[4][2];
  f32x4 acc[8][4];
#pragma unroll
  for (int m = 0; m < 8; ++m)
#pragma unroll
    for (int n = 0; n < 4; ++n) acc[m][n] = (f32x4){0.f, 0.f, 0.f, 0.f};

#define LDA(bufi, mg) do { \
    _Pragma("unroll") for (int mm = 0; mm < 4; ++mm) { \
      aF[mm][0] = *(const bf16x8*)&lds[bufi][0][mg][aRow + mm * 1024 + cbi0]; \
      aF[mm][1] = *(const bf16x8*)&lds[bufi][0][mg][aRow + mm * 1024 + cbi1]; \
    } } while (0)

#define LDB(bufi, np) do { \
    _Pragma("unroll") for (int nn = 0; nn < 2; ++nn) { \
      bF[(np) * 2 + nn][0] = *(const bf16x8*)&lds[bufi][1][np][bRow + nn * 1024 + cbi0]; \
      bF[(np) * 2 + nn][1] = *(const bf16x8*)&lds[bufi][1][np][bRow + nn * 1024 + cbi1]; \
    } } while (0)

#define MFMA_Q(mg, np) do { \
    __builtin_amdgcn_s_setprio(1); \
    _Pragma("unroll") for (int mm = 0; mm < 4; ++mm) \
    _Pragma("unroll") for (int nn = 0; nn < 2; ++nn) { \
      f32x4 c = acc[(mg) * 4 + mm][(np) * 2 + nn]; \
      c = __builtin_amdgcn_mfma_f32_16x16x32_bf16(aF[mm][0], bF[(np) * 2 + nn][0], c, 0, 0, 0); \
      c = __builtin_amdgcn_mfma_f32_16x16x32_bf16(aF[mm][1], bF[(np) * 2 + nn][1], c, 0, 0, 0); \
      acc[(mg) * 4 + mm][(np) * 2 + nn] = c; \
    } \
    __builtin_amdgcn_s_setprio(0); } while (0)

  // ---- prologue: tile0 complete, tile1 h0 halves ----
  STAGE_A(0, 0, 0); STAGE_B(0, 0, 0);
  STAGE_A(0, 1, 0); STAGE_B(0, 1, 0);
  STAGE_A(1, 0, 1); STAGE_B(1, 0, 1);
  VM(8);
  BAR();

  const int NT = K >> 6;  // 64-wide K-tiles (even count required; 2048/64=32)
  for (int i = 0; i < (NT >> 1); ++i) {
    const int t1  = 2 * i + 1;
    const int tn0 = (2 * i + 2 < NT) ? 2 * i + 2 : NT - 1;
    const int tn1 = (2 * i + 3 < NT) ? 2 * i + 3 : NT - 1;
    // P1
    LDA(0, 0); LDB(0, 0); STAGE_A(1, 1, t1); VM(6);
    BAR(); MFMA_Q(0, 0); BAR();
    // P2
    LDB(0, 1); STAGE_B(1, 1, t1);
    BAR(); MFMA_Q(0, 1); BAR();
    // P3
    LDA(0, 1); STAGE_A(0, 0, tn0);
    BAR(); MFMA_Q(1, 0); BAR();
    // P4
    STAGE_B(0, 0, tn0); VM(8);
    BAR(); MFMA_Q(1, 1); BAR();
    // P5
    LDA(1, 0); LDB(1, 0); STAGE_A(0, 1, tn0); VM(6);
    BAR(); MFMA_Q(0, 0); BAR();
    // P6
    LDB(1, 1); STAGE_B(0, 1, tn0);
    BAR(); MFMA_Q(0, 1); BAR();
    // P7
    LDA(1, 1); STAGE_A(1, 0, tn1);
    BAR(); MFMA_Q(1, 0); BAR();
    // P8
    STAGE_B(1, 0, tn1); VM(8);
    BAR(); MFMA_Q(1, 1); BAR();
  }
  asm volatile("s_waitcnt vmcnt(0)" ::: "memory");  // drain DMAs before exit

  // ---- epilogue: C = acc*scale[col] + bias[col] ----
  const int crowBase = mBase + wm * 128 + kq * 4;
  const int ccolBase = nBase + wn * 64 + fr;
#pragma unroll
  for (int n = 0; n < 4; ++n) {
    const int gc = ccolBase + n * 16;
    const float sc = scale[gc];
    const float bi = bias[gc];
#pragma unroll
    for (int m = 0; m < 8; ++m) {
      const int r0 = crowBase + m * 16;
#pragma unroll
      for (int r = 0; r < 4; ++r)
        C[(size_t)(r0 + r) * (size_t)N + (size_t)gc] = acc[m][n][r] * sc + bi;
    }
  }
#undef STAGE_A
#undef STAGE_B
#undef LDA
#undef LDB
#undef MFMA_Q
}

extern "C" void kernel_launch(void* const* d_in, const int* in_sizes, int n_in,
                              void* d_out, int out_size, void* d_ws, size_t ws_size,
                              hipStream_t stream) {
  const float* x         = (const float*)d_in[0];  // [B,S,Din]
  const float* weight    = (const float*)d_in[1];  // [Dout,Din]
  const float* row_scale = (const float*)d_in[2];  // [Dout,1]
  const float* bias      = (const float*)d_in[3];  // [Dout]
  const float* g         = (const float*)d_in[4];  // [Din]
  float* out = (float*)d_out;

  const int Din  = in_sizes[4];         // 2048
  const int Dout = in_sizes[3];         // 2048
  const int Mrows = in_sizes[0] / Din;  // 16384

  char* ws = (char*)d_ws;
  unsigned short* wq = (unsigned short*)ws;
  unsigned short* xn = (unsigned short*)(ws + (size_t)Dout * Din * 2);
  float* scale = (float*)(ws + (size_t)Dout * Din * 2 + (size_t)Mrows * Din * 2);

  wquant_kernel<<<Dout, 256, 0, stream>>>(weight, row_scale, wq, scale, Din);
  xnorm_kernel<<<Mrows, 256, 0, stream>>>(x, g, xn, Din);
  const int grid = (Mrows / 256) * (Dout / 256);
  gemm_kernel<<<grid, 512, 0, stream>>>(xn, wq, scale, bias, out,
                                        Mrows, Dout, Din);
}